// Round 3
// baseline (4643.613 us; speedup 1.0000x reference)
//
#include <hip/hip_runtime.h>
#include <cmath>

#define T_STEPS 128
#define B_ENV   1024
#define OBS_D   63
#define HID     256
#define NA      6

// fixed workspace layout (float element offsets); xg chunk buffer follows
#define OFF_W1T   0                     // 64*256   (W1^T, row 63 zero-padded)
#define OFF_W2T   16384                 // 256*256
#define OFF_WIP   81920                 // 256*1024  Wip[k][t][m] = W_ih[m*256+t][k]
#define OFF_WHP   344064                // 256*1024  Whp[k][t][m] = W_hh[m*256+t][k]
#define OFF_BIAS  606208                // 1024      biasp[t*4+m] = (b_ih+b_hh)[m*256+t]
#define OFF_XGP   607232                // TC*1024*1024 floats (chunked xg, packed [row][t][m])

// ---------------------------------------------------------------- prep ------
__global__ void prep_kernel(const float* __restrict__ W1, const float* __restrict__ W2,
                            const float* __restrict__ W_ih, const float* __restrict__ b_ih,
                            const float* __restrict__ W_hh, const float* __restrict__ b_hh,
                            const float* __restrict__ h0, const float* __restrict__ c0,
                            float* __restrict__ W1T, float* __restrict__ W2T,
                            float* __restrict__ Wip, float* __restrict__ Whp,
                            float* __restrict__ biasp,
                            float* __restrict__ hstate, float* __restrict__ cstate)
{
    const int stride = gridDim.x * blockDim.x;
    const int idx0 = blockIdx.x * blockDim.x + threadIdx.x;
    for (int i = idx0; i < 64 * 256; i += stride) {
        int k = i >> 8, j = i & 255;
        W1T[i] = (k < OBS_D) ? W1[j * OBS_D + k] : 0.f;
    }
    for (int i = idx0; i < 256 * 256; i += stride) {
        int k = i >> 8, j = i & 255;
        W2T[i] = W2[j * 256 + k];
    }
    for (int i = idx0; i < 256 * 1024; i += stride) {
        int k = i >> 10, r = i & 1023;
        int t = r >> 2, m = r & 3;
        int j = m * 256 + t;
        Wip[i] = W_ih[j * 256 + k];
        Whp[i] = W_hh[j * 256 + k];
    }
    for (int i = idx0; i < 1024; i += stride) {
        int t = i >> 2, m = i & 3;
        int j = m * 256 + t;
        biasp[i] = b_ih[j] + b_hh[j];
    }
    // running LSTM state lives in d_out's hT/cT region
    for (int i = idx0; i < B_ENV * HID; i += stride) {
        hstate[i] = h0[i];
        cstate[i] = c0[i];
    }
}

// ------------------------------------------------- fused MLP -> xg ----------
// 32 rows per block, 256 threads. LDS: 8K + 32K + 32K = 72 KB (2 blocks/CU).
__global__ __launch_bounds__(256) void mlp_xg_kernel(
    const float* __restrict__ x, const float* __restrict__ b1, const float* __restrict__ b2,
    const float* __restrict__ W1T, const float* __restrict__ W2T,
    const float* __restrict__ Wip, const float* __restrict__ biasp,
    float* __restrict__ xgp, long grow0)
{
    __shared__ float xs[32][64];
    __shared__ float h1s[32][256];
    __shared__ float h2s[32][256];
    const int t = threadIdx.x;
    const long lrow0 = (long)blockIdx.x * 32;       // local (chunk) row
    const long row0 = grow0 + lrow0;                // global row into x

    for (int i = t; i < 32 * OBS_D; i += 256) {
        int r = i / OBS_D, k = i - r * OBS_D;
        xs[r][k] = x[row0 * OBS_D + i];
    }
    if (t < 32) xs[t][63] = 0.f;
    __syncthreads();

    // phase 1: h1 = tanh(x @ W1^T + b1); thread t owns column t
    float acc[32];
#pragma unroll
    for (int r = 0; r < 32; ++r) acc[r] = 0.f;
    for (int k0 = 0; k0 < 64; k0 += 4) {
        float w0 = W1T[(k0 + 0) * 256 + t];
        float w1 = W1T[(k0 + 1) * 256 + t];
        float w2 = W1T[(k0 + 2) * 256 + t];
        float w3 = W1T[(k0 + 3) * 256 + t];
#pragma unroll
        for (int r = 0; r < 32; ++r) {
            float4 hv = *(const float4*)&xs[r][k0];
            acc[r] += hv.x * w0 + hv.y * w1 + hv.z * w2 + hv.w * w3;
        }
    }
    {
        float b = b1[t];
#pragma unroll
        for (int r = 0; r < 32; ++r) h1s[r][t] = tanhf(acc[r] + b);
    }
    __syncthreads();

    // phase 2: h2 = tanh(h1 @ W2^T + b2)
#pragma unroll
    for (int r = 0; r < 32; ++r) acc[r] = 0.f;
    for (int k0 = 0; k0 < 256; k0 += 4) {
        float w0 = W2T[(k0 + 0) * 256 + t];
        float w1 = W2T[(k0 + 1) * 256 + t];
        float w2 = W2T[(k0 + 2) * 256 + t];
        float w3 = W2T[(k0 + 3) * 256 + t];
#pragma unroll
        for (int r = 0; r < 32; ++r) {
            float4 hv = *(const float4*)&h1s[r][k0];
            acc[r] += hv.x * w0 + hv.y * w1 + hv.z * w2 + hv.w * w3;
        }
    }
    {
        float b = b2[t];
#pragma unroll
        for (int r = 0; r < 32; ++r) h2s[r][t] = tanhf(acc[r] + b);
    }
    __syncthreads();

    // phase 3: xg = h2 @ W_ih^T + (b_ih+b_hh), packed [local_row][t][m]
    const float4 bias4 = *(const float4*)&biasp[4 * t];
    const float4* Wip4 = (const float4*)Wip;
#pragma unroll 1
    for (int g = 0; g < 2; ++g) {
        float4 a4[16];
#pragma unroll
        for (int r = 0; r < 16; ++r) a4[r] = make_float4(0.f, 0.f, 0.f, 0.f);
        for (int k0 = 0; k0 < 256; k0 += 4) {
            float4 w[4];
#pragma unroll
            for (int kk = 0; kk < 4; ++kk) w[kk] = Wip4[(k0 + kk) * 256 + t];
#pragma unroll
            for (int r = 0; r < 16; ++r) {
                float4 hv = *(const float4*)&h2s[g * 16 + r][k0];
                a4[r].x += hv.x * w[0].x + hv.y * w[1].x + hv.z * w[2].x + hv.w * w[3].x;
                a4[r].y += hv.x * w[0].y + hv.y * w[1].y + hv.z * w[2].y + hv.w * w[3].y;
                a4[r].z += hv.x * w[0].z + hv.y * w[1].z + hv.z * w[2].z + hv.w * w[3].z;
                a4[r].w += hv.x * w[0].w + hv.y * w[1].w + hv.z * w[2].w + hv.w * w[3].w;
            }
        }
#pragma unroll
        for (int r = 0; r < 16; ++r) {
            float4 o;
            o.x = a4[r].x + bias4.x;
            o.y = a4[r].y + bias4.y;
            o.z = a4[r].z + bias4.z;
            o.w = a4[r].w + bias4.w;
            *(float4*)&xgp[(lrow0 + g * 16 + r) * 1024 + 4 * t] = o;
        }
    }
}

// ------------------------------------------------- LSTM scan + heads --------
// 128 blocks x 256 threads; block owns 8 batch rows for nsteps steps.
// Thread t owns hidden unit t (gates i,f,g,o packed m=0..3) for its 8 rows.
// Running state is read from / written back to hstate/cstate (d_out region).
__global__ __launch_bounds__(256) void lstm_chunk_kernel(
    const float* __restrict__ xgp, const int* __restrict__ done,
    const float* __restrict__ Whp,
    const float* __restrict__ Wa, const float* __restrict__ ba,
    const float* __restrict__ Wc, const float* __restrict__ bc,
    float* __restrict__ out, float* __restrict__ hstate, float* __restrict__ cstate,
    int step0, int nsteps)
{
    __shared__ float hs[8][256];
    __shared__ float headW[7][256];
    __shared__ float headb[8];
    const int t = threadIdx.x;
    const int rb0 = blockIdx.x * 8;

    for (int i = t; i < NA * 256; i += 256) headW[i >> 8][i & 255] = Wa[i];
    headW[6][t] = Wc[t];
    if (t < NA) headb[t] = ba[t];
    else if (t == NA) headb[NA] = bc[0];

    float c[8];
#pragma unroll
    for (int r = 0; r < 8; ++r) {
        hs[r][t] = hstate[(rb0 + r) * 256 + t];
        c[r] = cstate[(rb0 + r) * 256 + t];
    }
    __syncthreads();

    const float4* Whp4 = (const float4*)Whp;
    const float4* xgp4 = (const float4*)xgp;

    for (int s = 0; s < nsteps; ++s) {
        const long growbase = (long)(step0 + s) * B_ENV + rb0;  // done/out index
        const long lrowbase = (long)s * B_ENV + rb0;            // xg chunk index

        float msk[8];
#pragma unroll
        for (int r = 0; r < 8; ++r) msk[r] = 1.f - (float)done[growbase + r];

        float4 xv[8];
#pragma unroll
        for (int r = 0; r < 8; ++r) xv[r] = xgp4[(lrowbase + r) * 256 + t];

        float4 acc[8];
#pragma unroll
        for (int r = 0; r < 8; ++r) acc[r] = make_float4(0.f, 0.f, 0.f, 0.f);

        // matvec: gates[r][m] = sum_k hs[r][k] * Whp[k][t][m]  (prefetched W)
        float4 w0 = Whp4[0 * 256 + t], w1 = Whp4[1 * 256 + t];
        float4 w2 = Whp4[2 * 256 + t], w3 = Whp4[3 * 256 + t];
#pragma unroll 2
        for (int k0 = 0; k0 < 256; k0 += 4) {
            float4 cw0 = w0, cw1 = w1, cw2 = w2, cw3 = w3;
            if (k0 + 4 < 256) {
                w0 = Whp4[(k0 + 4) * 256 + t];
                w1 = Whp4[(k0 + 5) * 256 + t];
                w2 = Whp4[(k0 + 6) * 256 + t];
                w3 = Whp4[(k0 + 7) * 256 + t];
            }
            float4 hv[8];
#pragma unroll
            for (int r = 0; r < 8; ++r) hv[r] = *(const float4*)&hs[r][k0];
#pragma unroll
            for (int r = 0; r < 8; ++r) {
                acc[r].x += hv[r].x * cw0.x + hv[r].y * cw1.x + hv[r].z * cw2.x + hv[r].w * cw3.x;
                acc[r].y += hv[r].x * cw0.y + hv[r].y * cw1.y + hv[r].z * cw2.y + hv[r].w * cw3.y;
                acc[r].z += hv[r].x * cw0.z + hv[r].y * cw1.z + hv[r].z * cw2.z + hv[r].w * cw3.z;
                acc[r].w += hv[r].x * cw0.w + hv[r].y * cw1.w + hv[r].z * cw2.w + hv[r].w * cw3.w;
            }
        }
        __syncthreads();   // all matvec reads of hs complete

#pragma unroll
        for (int r = 0; r < 8; ++r) {
            float gi = xv[r].x + msk[r] * acc[r].x;
            float gf = xv[r].y + msk[r] * acc[r].y;
            float gg = xv[r].z + msk[r] * acc[r].z;
            float go = xv[r].w + msk[r] * acc[r].w;
            float si = 1.f / (1.f + expf(-gi));
            float sf = 1.f / (1.f + expf(-gf));
            float so = 1.f / (1.f + expf(-go));
            float cn = sf * (c[r] * msk[r]) + si * tanhf(gg);
            c[r] = cn;
            hs[r][t] = so * tanhf(cn);
        }
        __syncthreads();   // hs updated for heads + next step

        // heads: 56 dots (8 rows x 7 outputs), 4 lanes each
        if (t < 224) {
            const int task = t >> 2, l4 = t & 3;
            const int r = task / 7, a = task - r * 7;
            const int kb = l4 * 64;
            float p = 0.f;
#pragma unroll
            for (int k = 0; k < 64; k += 4) {
                float4 hv = *(const float4*)&hs[r][kb + k];
                float4 wv = *(const float4*)&headW[a][kb + k];
                p += hv.x * wv.x + hv.y * wv.y + hv.z * wv.z + hv.w * wv.w;
            }
            p += __shfl_down(p, 1, 4);
            p += __shfl_down(p, 2, 4);
            if (l4 == 0) out[(growbase + r) * 7 + a] = p + headb[a];
        }
    }

#pragma unroll
    for (int r = 0; r < 8; ++r) {
        hstate[(rb0 + r) * 256 + t] = hs[r][t];
        cstate[(rb0 + r) * 256 + t] = c[r];
    }
}

// ---------------------------------------------------------------- launch ----
extern "C" void kernel_launch(void* const* d_in, const int* in_sizes, int n_in,
                              void* d_out, int out_size, void* d_ws, size_t ws_size,
                              hipStream_t stream) {
    const float* x    = (const float*)d_in[0];
    const int*   done = (const int*)  d_in[1];
    const float* h0   = (const float*)d_in[2];
    const float* c0   = (const float*)d_in[3];
    const float* W1   = (const float*)d_in[4];
    const float* b1   = (const float*)d_in[5];
    const float* W2   = (const float*)d_in[6];
    const float* b2   = (const float*)d_in[7];
    const float* W_ih = (const float*)d_in[8];
    const float* b_ih = (const float*)d_in[9];
    const float* W_hh = (const float*)d_in[10];
    const float* b_hh = (const float*)d_in[11];
    const float* Wa   = (const float*)d_in[12];
    const float* ba   = (const float*)d_in[13];
    const float* Wc   = (const float*)d_in[14];
    const float* bc   = (const float*)d_in[15];

    float* ws    = (float*)d_ws;
    float* W1T   = ws + OFF_W1T;
    float* W2T   = ws + OFF_W2T;
    float* Wip   = ws + OFF_WIP;
    float* Whp   = ws + OFF_WHP;
    float* biasp = ws + OFF_BIAS;
    float* xgp   = ws + OFF_XGP;

    float* out = (float*)d_out;
    float* hT  = out + (size_t)T_STEPS * B_ENV * (NA + 1);
    float* cT  = hT + (size_t)B_ENV * HID;

    // largest power-of-two chunk (in timesteps) whose xg buffer fits d_ws
    const size_t ws_floats = ws_size / sizeof(float);
    int TC = T_STEPS;
    while (TC > 1 && (size_t)OFF_XGP + (size_t)TC * B_ENV * 4 * HID > ws_floats) TC >>= 1;

    prep_kernel<<<512, 256, 0, stream>>>(W1, W2, W_ih, b_ih, W_hh, b_hh, h0, c0,
                                         W1T, W2T, Wip, Whp, biasp, hT, cT);
    for (int step0 = 0; step0 < T_STEPS; step0 += TC) {
        mlp_xg_kernel<<<(TC * B_ENV) / 32, 256, 0, stream>>>(
            x, b1, b2, W1T, W2T, Wip, biasp, xgp, (long)step0 * B_ENV);
        lstm_chunk_kernel<<<B_ENV / 8, 256, 0, stream>>>(
            xgp, done, Whp, Wa, ba, Wc, bc, out, hT, cT, step0, TC);
    }
}

// Round 5
// 3234.885 us; speedup vs baseline: 1.4355x; 1.4355x over previous
//
#include <hip/hip_runtime.h>
#include <cmath>

#define T_STEPS 128
#define B_ENV   1024
#define OBS_D   63
#define HID     256
#define NA      6

// fixed workspace layout (float element offsets); xg chunk buffer follows
#define OFF_W1T   0                     // 64*256   (W1^T, row 63 zero-padded)
#define OFF_W2T   16384                 // 256*256
#define OFF_WIP   81920                 // 256*1024  Wip[k][t][m] = W_ih[m*256+t][k]
#define OFF_WHP   344064                // 256*1024  Whp[k][t][m] = W_hh[m*256+t][k]
#define OFF_BIAS  606208                // 1024      biasp[t*4+m] = (b_ih+b_hh)[m*256+t]
#define OFF_XGP   607232                // TC*1024*1024 floats (chunked xg, packed [row][t][m])

#define HS_PAD 264                      // 264%32=8 -> rows land on distinct banks

// ---------------------------------------------------------------- prep ------
__global__ void prep_kernel(const float* __restrict__ W1, const float* __restrict__ W2,
                            const float* __restrict__ W_ih, const float* __restrict__ b_ih,
                            const float* __restrict__ W_hh, const float* __restrict__ b_hh,
                            const float* __restrict__ h0, const float* __restrict__ c0,
                            float* __restrict__ W1T, float* __restrict__ W2T,
                            float* __restrict__ Wip, float* __restrict__ Whp,
                            float* __restrict__ biasp,
                            float* __restrict__ hstate, float* __restrict__ cstate)
{
    const int stride = gridDim.x * blockDim.x;
    const int idx0 = blockIdx.x * blockDim.x + threadIdx.x;
    for (int i = idx0; i < 64 * 256; i += stride) {
        int k = i >> 8, j = i & 255;
        W1T[i] = (k < OBS_D) ? W1[j * OBS_D + k] : 0.f;
    }
    for (int i = idx0; i < 256 * 256; i += stride) {
        int k = i >> 8, j = i & 255;
        W2T[i] = W2[j * 256 + k];
    }
    for (int i = idx0; i < 256 * 1024; i += stride) {
        int k = i >> 10, r = i & 1023;
        int t = r >> 2, m = r & 3;
        int j = m * 256 + t;
        Wip[i] = W_ih[j * 256 + k];
        Whp[i] = W_hh[j * 256 + k];
    }
    for (int i = idx0; i < 1024; i += stride) {
        int t = i >> 2, m = i & 3;
        int j = m * 256 + t;
        biasp[i] = b_ih[j] + b_hh[j];
    }
    // running LSTM state lives in d_out's hT/cT region
    for (int i = idx0; i < B_ENV * HID; i += stride) {
        hstate[i] = h0[i];
        cstate[i] = c0[i];
    }
}

// ------------------------------------------------- fused MLP -> xg ----------
// 32 rows per block, 256 threads. LDS: 8K + 32K + 32K = 72 KB (2 blocks/CU).
__global__ __launch_bounds__(256) void mlp_xg_kernel(
    const float* __restrict__ x, const float* __restrict__ b1, const float* __restrict__ b2,
    const float* __restrict__ W1T, const float* __restrict__ W2T,
    const float* __restrict__ Wip, const float* __restrict__ biasp,
    float* __restrict__ xgp, long grow0)
{
    __shared__ float xs[32][64];
    __shared__ float h1s[32][256];
    __shared__ float h2s[32][256];
    const int t = threadIdx.x;
    const long lrow0 = (long)blockIdx.x * 32;       // local (chunk) row
    const long row0 = grow0 + lrow0;                // global row into x

    for (int i = t; i < 32 * OBS_D; i += 256) {
        int r = i / OBS_D, k = i - r * OBS_D;
        xs[r][k] = x[row0 * OBS_D + i];
    }
    if (t < 32) xs[t][63] = 0.f;
    __syncthreads();

    // phase 1: h1 = tanh(x @ W1^T + b1); thread t owns column t
    float acc[32];
#pragma unroll
    for (int r = 0; r < 32; ++r) acc[r] = 0.f;
    for (int k0 = 0; k0 < 64; k0 += 4) {
        float w0 = W1T[(k0 + 0) * 256 + t];
        float w1 = W1T[(k0 + 1) * 256 + t];
        float w2 = W1T[(k0 + 2) * 256 + t];
        float w3 = W1T[(k0 + 3) * 256 + t];
#pragma unroll
        for (int r = 0; r < 32; ++r) {
            float4 hv = *(const float4*)&xs[r][k0];
            acc[r] += hv.x * w0 + hv.y * w1 + hv.z * w2 + hv.w * w3;
        }
    }
    {
        float b = b1[t];
#pragma unroll
        for (int r = 0; r < 32; ++r) h1s[r][t] = tanhf(acc[r] + b);
    }
    __syncthreads();

    // phase 2: h2 = tanh(h1 @ W2^T + b2)
#pragma unroll
    for (int r = 0; r < 32; ++r) acc[r] = 0.f;
    for (int k0 = 0; k0 < 256; k0 += 4) {
        float w0 = W2T[(k0 + 0) * 256 + t];
        float w1 = W2T[(k0 + 1) * 256 + t];
        float w2 = W2T[(k0 + 2) * 256 + t];
        float w3 = W2T[(k0 + 3) * 256 + t];
#pragma unroll
        for (int r = 0; r < 32; ++r) {
            float4 hv = *(const float4*)&h1s[r][k0];
            acc[r] += hv.x * w0 + hv.y * w1 + hv.z * w2 + hv.w * w3;
        }
    }
    {
        float b = b2[t];
#pragma unroll
        for (int r = 0; r < 32; ++r) h2s[r][t] = tanhf(acc[r] + b);
    }
    __syncthreads();

    // phase 3: xg = h2 @ W_ih^T + (b_ih+b_hh), packed [local_row][t][m]
    const float4 bias4 = *(const float4*)&biasp[4 * t];
    const float4* Wip4 = (const float4*)Wip;
#pragma unroll 1
    for (int g = 0; g < 2; ++g) {
        float4 a4[16];
#pragma unroll
        for (int r = 0; r < 16; ++r) a4[r] = make_float4(0.f, 0.f, 0.f, 0.f);
        for (int k0 = 0; k0 < 256; k0 += 4) {
            float4 w[4];
#pragma unroll
            for (int kk = 0; kk < 4; ++kk) w[kk] = Wip4[(k0 + kk) * 256 + t];
#pragma unroll
            for (int r = 0; r < 16; ++r) {
                float4 hv = *(const float4*)&h2s[g * 16 + r][k0];
                a4[r].x += hv.x * w[0].x + hv.y * w[1].x + hv.z * w[2].x + hv.w * w[3].x;
                a4[r].y += hv.x * w[0].y + hv.y * w[1].y + hv.z * w[2].y + hv.w * w[3].y;
                a4[r].z += hv.x * w[0].z + hv.y * w[1].z + hv.z * w[2].z + hv.w * w[3].z;
                a4[r].w += hv.x * w[0].w + hv.y * w[1].w + hv.z * w[2].w + hv.w * w[3].w;
            }
        }
#pragma unroll
        for (int r = 0; r < 16; ++r) {
            float4 o;
            o.x = a4[r].x + bias4.x;
            o.y = a4[r].y + bias4.y;
            o.z = a4[r].z + bias4.z;
            o.w = a4[r].w + bias4.w;
            *(float4*)&xgp[(lrow0 + g * 16 + r) * 1024 + 4 * t] = o;
        }
    }
}

// ------------------------------------------------- LSTM scan + heads --------
// 256 blocks x 256 threads; block owns 4 batch rows for nsteps steps.
// Thread t owns hidden unit t (gates i,f,g,o packed m=0..3) for its 4 rows.
// Running state is read from / written back to hstate/cstate (d_out region).
__global__ __launch_bounds__(256) void lstm_chunk_kernel(
    const float* __restrict__ xgp, const int* __restrict__ done,
    const float* __restrict__ Whp,
    const float* __restrict__ Wa, const float* __restrict__ ba,
    const float* __restrict__ Wc, const float* __restrict__ bc,
    float* __restrict__ out, float* __restrict__ hstate, float* __restrict__ cstate,
    int step0, int nsteps)
{
    __shared__ float hs[4][HS_PAD];     // padded: rows on distinct LDS banks
    __shared__ float headW[7][256];
    __shared__ float headb[8];
    const int t = threadIdx.x;
    const int rb0 = blockIdx.x * 4;

    for (int i = t; i < NA * 256; i += 256) headW[i >> 8][i & 255] = Wa[i];
    headW[6][t] = Wc[t];
    if (t < NA) headb[t] = ba[t];
    else if (t == NA) headb[NA] = bc[0];

    float c[4];
#pragma unroll
    for (int r = 0; r < 4; ++r) {
        hs[r][t] = hstate[(rb0 + r) * 256 + t];
        c[r] = cstate[(rb0 + r) * 256 + t];
    }
    __syncthreads();

    const float4* Whp4 = (const float4*)Whp;
    const float4* xgp4 = (const float4*)xgp;

    for (int s = 0; s < nsteps; ++s) {
        const long growbase = (long)(step0 + s) * B_ENV + rb0;  // done/out index
        const long lrowbase = (long)s * B_ENV + rb0;            // xg chunk index

        float msk[4];
#pragma unroll
        for (int r = 0; r < 4; ++r) msk[r] = 1.f - (float)done[growbase + r];

        float4 xv[4];
#pragma unroll
        for (int r = 0; r < 4; ++r) xv[r] = xgp4[(lrowbase + r) * 256 + t];

        float4 acc[4];
#pragma unroll
        for (int r = 0; r < 4; ++r) acc[r] = make_float4(0.f, 0.f, 0.f, 0.f);

        // matvec: gates[r][m] = sum_k hs[r][k] * Whp[k][t][m]  (prefetched W)
        float4 w0 = Whp4[0 * 256 + t], w1 = Whp4[1 * 256 + t];
        float4 w2 = Whp4[2 * 256 + t], w3 = Whp4[3 * 256 + t];
#pragma unroll 4
        for (int k0 = 0; k0 < 256; k0 += 4) {
            float4 cw0 = w0, cw1 = w1, cw2 = w2, cw3 = w3;
            if (k0 + 4 < 256) {
                w0 = Whp4[(k0 + 4) * 256 + t];
                w1 = Whp4[(k0 + 5) * 256 + t];
                w2 = Whp4[(k0 + 6) * 256 + t];
                w3 = Whp4[(k0 + 7) * 256 + t];
            }
            float4 hv[4];
#pragma unroll
            for (int r = 0; r < 4; ++r) hv[r] = *(const float4*)&hs[r][k0];
#pragma unroll
            for (int r = 0; r < 4; ++r) {
                acc[r].x += hv[r].x * cw0.x + hv[r].y * cw1.x + hv[r].z * cw2.x + hv[r].w * cw3.x;
                acc[r].y += hv[r].x * cw0.y + hv[r].y * cw1.y + hv[r].z * cw2.y + hv[r].w * cw3.y;
                acc[r].z += hv[r].x * cw0.z + hv[r].y * cw1.z + hv[r].z * cw2.z + hv[r].w * cw3.z;
                acc[r].w += hv[r].x * cw0.w + hv[r].y * cw1.w + hv[r].z * cw2.w + hv[r].w * cw3.w;
            }
        }
        __syncthreads();   // all matvec reads of hs complete

#pragma unroll
        for (int r = 0; r < 4; ++r) {
            float gi = xv[r].x + msk[r] * acc[r].x;
            float gf = xv[r].y + msk[r] * acc[r].y;
            float gg = xv[r].z + msk[r] * acc[r].z;
            float go = xv[r].w + msk[r] * acc[r].w;
            float si = 1.f / (1.f + expf(-gi));
            float sf = 1.f / (1.f + expf(-gf));
            float so = 1.f / (1.f + expf(-go));
            float cn = sf * (c[r] * msk[r]) + si * tanhf(gg);
            c[r] = cn;
            hs[r][t] = so * tanhf(cn);
        }
        __syncthreads();   // hs updated for heads + next step

        // heads: 28 dots (4 rows x 7 outputs), 4 lanes each
        if (t < 112) {
            const int task = t >> 2, l4 = t & 3;
            const int r = task / 7, a = task - r * 7;
            const int kb = l4 * 64;
            float p = 0.f;
#pragma unroll
            for (int k = 0; k < 64; k += 4) {
                float4 hv = *(const float4*)&hs[r][kb + k];
                float4 wv = *(const float4*)&headW[a][kb + k];
                p += hv.x * wv.x + hv.y * wv.y + hv.z * wv.z + hv.w * wv.w;
            }
            p += __shfl_down(p, 1, 4);
            p += __shfl_down(p, 2, 4);
            if (l4 == 0) out[(growbase + r) * 7 + a] = p + headb[a];
        }
    }

#pragma unroll
    for (int r = 0; r < 4; ++r) {
        hstate[(rb0 + r) * 256 + t] = hs[r][t];
        cstate[(rb0 + r) * 256 + t] = c[r];
    }
}

// ---------------------------------------------------------------- launch ----
extern "C" void kernel_launch(void* const* d_in, const int* in_sizes, int n_in,
                              void* d_out, int out_size, void* d_ws, size_t ws_size,
                              hipStream_t stream) {
    const float* x    = (const float*)d_in[0];
    const int*   done = (const int*)  d_in[1];
    const float* h0   = (const float*)d_in[2];
    const float* c0   = (const float*)d_in[3];
    const float* W1   = (const float*)d_in[4];
    const float* b1   = (const float*)d_in[5];
    const float* W2   = (const float*)d_in[6];
    const float* b2   = (const float*)d_in[7];
    const float* W_ih = (const float*)d_in[8];
    const float* b_ih = (const float*)d_in[9];
    const float* W_hh = (const float*)d_in[10];
    const float* b_hh = (const float*)d_in[11];
    const float* Wa   = (const float*)d_in[12];
    const float* ba   = (const float*)d_in[13];
    const float* Wc   = (const float*)d_in[14];
    const float* bc   = (const float*)d_in[15];

    float* ws    = (float*)d_ws;
    float* W1T   = ws + OFF_W1T;
    float* W2T   = ws + OFF_W2T;
    float* Wip   = ws + OFF_WIP;
    float* Whp   = ws + OFF_WHP;
    float* biasp = ws + OFF_BIAS;
    float* xgp   = ws + OFF_XGP;

    float* out = (float*)d_out;
    float* hT  = out + (size_t)T_STEPS * B_ENV * (NA + 1);
    float* cT  = hT + (size_t)B_ENV * HID;

    // largest power-of-two chunk (in timesteps) whose xg buffer fits d_ws
    const size_t ws_floats = ws_size / sizeof(float);
    int TC = T_STEPS;
    while (TC > 1 && (size_t)OFF_XGP + (size_t)TC * B_ENV * 4 * HID > ws_floats) TC >>= 1;

    prep_kernel<<<512, 256, 0, stream>>>(W1, W2, W_ih, b_ih, W_hh, b_hh, h0, c0,
                                         W1T, W2T, Wip, Whp, biasp, hT, cT);
    for (int step0 = 0; step0 < T_STEPS; step0 += TC) {
        mlp_xg_kernel<<<(TC * B_ENV) / 32, 256, 0, stream>>>(
            x, b1, b2, W1T, W2T, Wip, biasp, xgp, (long)step0 * B_ENV);
        lstm_chunk_kernel<<<B_ENV / 4, 256, 0, stream>>>(
            xgp, done, Whp, Wa, ba, Wc, bc, out, hT, cT, step0, TC);
    }
}

// Round 7
// 3131.037 us; speedup vs baseline: 1.4831x; 1.0332x over previous
//
#include <hip/hip_runtime.h>
#include <cmath>

#define T_STEPS 128
#define B_ENV   1024
#define OBS_D   63
#define HID     256
#define NA      6

// workspace layout (float-slot offsets)
#define OFF_W1T    0         // 16384   fp32 W1^T (row 63 zero-padded)
#define OFF_W2T    16384     // 65536   fp32 W2^T
#define OFF_WIP16  81920     // 131072  uints: half2 Wip16[kk][t*4+m] = W_ih[j][2kk..2kk+1], j=m*256+t
#define OFF_WHP16  212992    // 131072  uints: same packing of W_hh
#define OFF_BIAS   344064    // 1024    fp32 biasp[t*4+m] = (b_ih+b_hh)[m*256+t]
#define OFF_XGP    345088    // TC*1048576 fp32 xg (packed [row][t][m])
// hbuf (fp16 h_t, TC*262144 halfs) follows xgp

typedef _Float16 h2f __attribute__((ext_vector_type(2)));

static __device__ __forceinline__ float fdot2u(unsigned a, unsigned b, float c) {
    return __builtin_amdgcn_fdot2(__builtin_bit_cast(h2f, a),
                                  __builtin_bit_cast(h2f, b), c, false);
}
static __device__ __forceinline__ unsigned packh2(float a, float b) {
    _Float16 ha = (_Float16)a, hb = (_Float16)b;
    unsigned short ua = __builtin_bit_cast(unsigned short, ha);
    unsigned short ub = __builtin_bit_cast(unsigned short, hb);
    return (unsigned)ua | ((unsigned)ub << 16);
}

// ---------------------------------------------------------------- prep ------
__global__ void prep_kernel(const float* __restrict__ W1, const float* __restrict__ W2,
                            const float* __restrict__ W_ih, const float* __restrict__ b_ih,
                            const float* __restrict__ W_hh, const float* __restrict__ b_hh,
                            const float* __restrict__ h0, const float* __restrict__ c0,
                            float* __restrict__ W1T, float* __restrict__ W2T,
                            unsigned* __restrict__ Wip16, unsigned* __restrict__ Whp16,
                            float* __restrict__ biasp,
                            float* __restrict__ hstate, float* __restrict__ cstate)
{
    const int stride = gridDim.x * blockDim.x;
    const int idx0 = blockIdx.x * blockDim.x + threadIdx.x;
    for (int i = idx0; i < 64 * 256; i += stride) {
        int k = i >> 8, j = i & 255;
        W1T[i] = (k < OBS_D) ? W1[j * OBS_D + k] : 0.f;
    }
    for (int i = idx0; i < 256 * 256; i += stride) {
        int k = i >> 8, j = i & 255;
        W2T[i] = W2[j * 256 + k];
    }
    for (int i = idx0; i < 128 * 1024; i += stride) {
        int kk = i >> 10, r = i & 1023;
        int t = r >> 2, m = r & 3;
        int j = m * 256 + t;
        Wip16[i] = packh2(W_ih[j * 256 + 2 * kk], W_ih[j * 256 + 2 * kk + 1]);
        Whp16[i] = packh2(W_hh[j * 256 + 2 * kk], W_hh[j * 256 + 2 * kk + 1]);
    }
    for (int i = idx0; i < 1024; i += stride) {
        int t = i >> 2, m = i & 3;
        int j = m * 256 + t;
        biasp[i] = b_ih[j] + b_hh[j];
    }
    for (int i = idx0; i < B_ENV * HID; i += stride) {
        hstate[i] = h0[i];
        cstate[i] = c0[i];
    }
}

// ------------------------------------------------- fused MLP -> xg ----------
// 32 rows/block, 256 threads. LDS: 8K + 32K + 16.9K = 57 KB (2 blocks/CU).
__global__ __launch_bounds__(256) void mlp_xg_kernel(
    const float* __restrict__ x, const float* __restrict__ b1, const float* __restrict__ b2,
    const float* __restrict__ W1T, const float* __restrict__ W2T,
    const unsigned* __restrict__ Wip16, const float* __restrict__ biasp,
    float* __restrict__ xgp, long grow0)
{
    __shared__ float xs[32][64];
    __shared__ float h1s[32][256];
    __shared__ unsigned h2s2[32][132];   // half2 h2, 128 words + pad
    const int t = threadIdx.x;
    const long lrow0 = (long)blockIdx.x * 32;
    const long row0 = grow0 + lrow0;

    for (int i = t; i < 32 * OBS_D; i += 256) {
        int r = i / OBS_D, k = i - r * OBS_D;
        xs[r][k] = x[row0 * OBS_D + i];
    }
    if (t < 32) xs[t][63] = 0.f;
    __syncthreads();

    // phase 1: h1 = tanh(x @ W1^T + b1); thread t owns column t
    float acc[32];
#pragma unroll
    for (int r = 0; r < 32; ++r) acc[r] = 0.f;
    for (int k0 = 0; k0 < 64; k0 += 4) {
        float w0 = W1T[(k0 + 0) * 256 + t];
        float w1 = W1T[(k0 + 1) * 256 + t];
        float w2 = W1T[(k0 + 2) * 256 + t];
        float w3 = W1T[(k0 + 3) * 256 + t];
#pragma unroll
        for (int r = 0; r < 32; ++r) {
            float4 hv = *(const float4*)&xs[r][k0];
            acc[r] += hv.x * w0 + hv.y * w1 + hv.z * w2 + hv.w * w3;
        }
    }
    {
        float b = b1[t];
#pragma unroll
        for (int r = 0; r < 32; ++r) h1s[r][t] = tanhf(acc[r] + b);
    }
    __syncthreads();

    // phase 2: h2 = tanh(h1 @ W2^T + b2), stored to LDS as fp16
#pragma unroll
    for (int r = 0; r < 32; ++r) acc[r] = 0.f;
    for (int k0 = 0; k0 < 256; k0 += 4) {
        float w0 = W2T[(k0 + 0) * 256 + t];
        float w1 = W2T[(k0 + 1) * 256 + t];
        float w2 = W2T[(k0 + 2) * 256 + t];
        float w3 = W2T[(k0 + 3) * 256 + t];
#pragma unroll
        for (int r = 0; r < 32; ++r) {
            float4 hv = *(const float4*)&h1s[r][k0];
            acc[r] += hv.x * w0 + hv.y * w1 + hv.z * w2 + hv.w * w3;
        }
    }
    {
        float b = b2[t];
#pragma unroll
        for (int r = 0; r < 32; ++r)
            ((_Float16*)&h2s2[r][0])[t] = (_Float16)tanhf(acc[r] + b);
    }
    __syncthreads();

    // phase 3: xg = h2 @ W_ih^T + bias via v_dot2_f32_f16
    const float4 bias4 = *(const float4*)&biasp[4 * t];
    const uint4* Wip4 = (const uint4*)Wip16;
#pragma unroll 1
    for (int g = 0; g < 2; ++g) {
        float a4[16][4];
#pragma unroll
        for (int r = 0; r < 16; ++r)
#pragma unroll
            for (int m = 0; m < 4; ++m) a4[r][m] = 0.f;
        uint4 w = Wip4[t];
#pragma unroll 4
        for (int kk = 0; kk < 128; ++kk) {
            uint4 cw = w;
            if (kk + 1 < 128) w = Wip4[(kk + 1) * 256 + t];
#pragma unroll
            for (int r = 0; r < 16; ++r) {
                unsigned hv = h2s2[g * 16 + r][kk];
                a4[r][0] = fdot2u(hv, cw.x, a4[r][0]);
                a4[r][1] = fdot2u(hv, cw.y, a4[r][1]);
                a4[r][2] = fdot2u(hv, cw.z, a4[r][2]);
                a4[r][3] = fdot2u(hv, cw.w, a4[r][3]);
            }
        }
#pragma unroll
        for (int r = 0; r < 16; ++r) {
            float4 o;
            o.x = a4[r][0] + bias4.x;
            o.y = a4[r][1] + bias4.y;
            o.z = a4[r][2] + bias4.z;
            o.w = a4[r][3] + bias4.w;
            *(float4*)&xgp[(lrow0 + g * 16 + r) * 1024 + 4 * t] = o;
        }
    }
}

// ------------------------------------------------- LSTM scan ----------------
// 256 blocks x 256 threads; block owns 4 batch rows. fp16 W/h matvec via dot2,
// fp32 cell state and gate math. h_t streamed to hbuf (fp16) for heads kernel.
__global__ __launch_bounds__(256) void lstm_chunk_kernel(
    const float* __restrict__ xgp, const int* __restrict__ done,
    const unsigned* __restrict__ Whp16,
    _Float16* __restrict__ hbuf,
    float* __restrict__ hstate, float* __restrict__ cstate,
    int step0, int nsteps)
{
    __shared__ unsigned hs2[4][132];     // half2 h, 128 words + pad
    const int t = threadIdx.x;
    const int rb0 = blockIdx.x * 4;

    float c[4], hlast[4];
#pragma unroll
    for (int r = 0; r < 4; ++r) {
        float hv = hstate[(rb0 + r) * 256 + t];
        hlast[r] = hv;
        ((_Float16*)&hs2[r][0])[t] = (_Float16)hv;
        c[r] = cstate[(rb0 + r) * 256 + t];
    }
    __syncthreads();

    const uint4* W4 = (const uint4*)Whp16;
    const float4* xgp4 = (const float4*)xgp;

    for (int s = 0; s < nsteps; ++s) {
        const long growbase = (long)(step0 + s) * B_ENV + rb0;  // done index
        const long lrowbase = (long)s * B_ENV + rb0;            // xg/hbuf index

        float msk[4];
#pragma unroll
        for (int r = 0; r < 4; ++r) msk[r] = 1.f - (float)done[growbase + r];

        float4 xv[4];
#pragma unroll
        for (int r = 0; r < 4; ++r) xv[r] = xgp4[(lrowbase + r) * 256 + t];

        float acc[4][4];
#pragma unroll
        for (int r = 0; r < 4; ++r)
#pragma unroll
            for (int m = 0; m < 4; ++m) acc[r][m] = 0.f;

        uint4 w = W4[t];
#pragma unroll 4
        for (int kk = 0; kk < 128; ++kk) {
            uint4 cw = w;
            if (kk + 1 < 128) w = W4[(kk + 1) * 256 + t];
            unsigned hv0 = hs2[0][kk], hv1 = hs2[1][kk];
            unsigned hv2 = hs2[2][kk], hv3 = hs2[3][kk];
            acc[0][0] = fdot2u(hv0, cw.x, acc[0][0]);
            acc[0][1] = fdot2u(hv0, cw.y, acc[0][1]);
            acc[0][2] = fdot2u(hv0, cw.z, acc[0][2]);
            acc[0][3] = fdot2u(hv0, cw.w, acc[0][3]);
            acc[1][0] = fdot2u(hv1, cw.x, acc[1][0]);
            acc[1][1] = fdot2u(hv1, cw.y, acc[1][1]);
            acc[1][2] = fdot2u(hv1, cw.z, acc[1][2]);
            acc[1][3] = fdot2u(hv1, cw.w, acc[1][3]);
            acc[2][0] = fdot2u(hv2, cw.x, acc[2][0]);
            acc[2][1] = fdot2u(hv2, cw.y, acc[2][1]);
            acc[2][2] = fdot2u(hv2, cw.z, acc[2][2]);
            acc[2][3] = fdot2u(hv2, cw.w, acc[2][3]);
            acc[3][0] = fdot2u(hv3, cw.x, acc[3][0]);
            acc[3][1] = fdot2u(hv3, cw.y, acc[3][1]);
            acc[3][2] = fdot2u(hv3, cw.z, acc[3][2]);
            acc[3][3] = fdot2u(hv3, cw.w, acc[3][3]);
        }
        __syncthreads();   // matvec reads of hs2 complete

#pragma unroll
        for (int r = 0; r < 4; ++r) {
            float gi = xv[r].x + msk[r] * acc[r][0];
            float gf = xv[r].y + msk[r] * acc[r][1];
            float gg = xv[r].z + msk[r] * acc[r][2];
            float go = xv[r].w + msk[r] * acc[r][3];
            float si = 1.f / (1.f + expf(-gi));
            float sf = 1.f / (1.f + expf(-gf));
            float so = 1.f / (1.f + expf(-go));
            float cn = sf * (c[r] * msk[r]) + si * tanhf(gg);
            c[r] = cn;
            float hn = so * tanhf(cn);
            hlast[r] = hn;
            ((_Float16*)&hs2[r][0])[t] = (_Float16)hn;
            hbuf[(lrowbase + r) * 256 + t] = (_Float16)hn;
        }
        __syncthreads();   // hs2 updated for next step
    }

#pragma unroll
    for (int r = 0; r < 4; ++r) {
        hstate[(rb0 + r) * 256 + t] = hlast[r];
        cstate[(rb0 + r) * 256 + t] = c[r];
    }
}

// ------------------------------------------------- heads --------------------
// 64 rows/block; actor+critic = 7 dots of 256 per row, fp16 dot2 from LDS.
__global__ __launch_bounds__(256) void heads_kernel(
    const _Float16* __restrict__ hbuf,
    const float* __restrict__ Wa, const float* __restrict__ ba,
    const float* __restrict__ Wc, const float* __restrict__ bc,
    float* __restrict__ out, int step0)
{
    __shared__ unsigned hsu[64][132];    // 64 rows of half2 h
    __shared__ unsigned hwu[7][132];     // 7 head rows as half2
    __shared__ float hbias[8];
    const int t = threadIdx.x;
    const long lrow0 = (long)blockIdx.x * 64;

    for (int i = t; i < 7 * 128; i += 256) {
        int a = i >> 7, kk = i & 127;
        float f0 = (a < 6) ? Wa[a * 256 + 2 * kk] : Wc[2 * kk];
        float f1 = (a < 6) ? Wa[a * 256 + 2 * kk + 1] : Wc[2 * kk + 1];
        hwu[a][kk] = packh2(f0, f1);
    }
    if (t < 7) hbias[t] = (t < 6) ? ba[t] : bc[0];

    const uint4* src = (const uint4*)(hbuf + lrow0 * 256);
    for (int i = t; i < 2048; i += 256) {
        int row = i >> 5, c8 = i & 31;
        *(uint4*)&hsu[row][c8 * 4] = src[i];
    }
    __syncthreads();

#pragma unroll 2
    for (int p = 0; p < 2; ++p) {
        int task = p * 256 + t;
        if (task < 448) {
            int row = task / 7, a = task - row * 7;
            float s = 0.f;
#pragma unroll 8
            for (int kk = 0; kk < 128; ++kk)
                s = fdot2u(hsu[row][kk], hwu[a][kk], s);
            out[((long)step0 * B_ENV + lrow0 + row) * 7 + a] = s + hbias[a];
        }
    }
}

// ---------------------------------------------------------------- launch ----
extern "C" void kernel_launch(void* const* d_in, const int* in_sizes, int n_in,
                              void* d_out, int out_size, void* d_ws, size_t ws_size,
                              hipStream_t stream) {
    const float* x    = (const float*)d_in[0];
    const int*   done = (const int*)  d_in[1];
    const float* h0   = (const float*)d_in[2];
    const float* c0   = (const float*)d_in[3];
    const float* W1   = (const float*)d_in[4];
    const float* b1   = (const float*)d_in[5];
    const float* W2   = (const float*)d_in[6];
    const float* b2   = (const float*)d_in[7];
    const float* W_ih = (const float*)d_in[8];
    const float* b_ih = (const float*)d_in[9];
    const float* W_hh = (const float*)d_in[10];
    const float* b_hh = (const float*)d_in[11];
    const float* Wa   = (const float*)d_in[12];
    const float* ba   = (const float*)d_in[13];
    const float* Wc   = (const float*)d_in[14];
    const float* bc   = (const float*)d_in[15];

    float* ws       = (float*)d_ws;
    float* W1T      = ws + OFF_W1T;
    float* W2T      = ws + OFF_W2T;
    unsigned* Wip16 = (unsigned*)(ws + OFF_WIP16);
    unsigned* Whp16 = (unsigned*)(ws + OFF_WHP16);
    float* biasp    = ws + OFF_BIAS;
    float* xgp      = ws + OFF_XGP;

    float* out = (float*)d_out;
    float* hT  = out + (size_t)T_STEPS * B_ENV * (NA + 1);
    float* cT  = hT + (size_t)B_ENV * HID;

    // largest power-of-two chunk: xgp (TC*1M fp32) + hbuf (TC*128K slots)
    const size_t ws_floats = ws_size / sizeof(float);
    int TC = T_STEPS;
    while (TC > 1 && (size_t)OFF_XGP + (size_t)TC * (1048576 + 131072) > ws_floats) TC >>= 1;
    _Float16* hbuf = (_Float16*)(ws + OFF_XGP + (size_t)TC * 1048576);

    prep_kernel<<<512, 256, 0, stream>>>(W1, W2, W_ih, b_ih, W_hh, b_hh, h0, c0,
                                         W1T, W2T, Wip16, Whp16, biasp, hT, cT);
    for (int step0 = 0; step0 < T_STEPS; step0 += TC) {
        mlp_xg_kernel<<<TC * 32, 256, 0, stream>>>(
            x, b1, b2, W1T, W2T, Wip16, biasp, xgp, (long)step0 * B_ENV);
        lstm_chunk_kernel<<<B_ENV / 4, 256, 0, stream>>>(
            xgp, done, Whp16, hbuf, hT, cT, step0, TC);
        heads_kernel<<<TC * 16, 256, 0, stream>>>(
            hbuf, Wa, ba, Wc, bc, out, step0);
    }
}

// Round 9
// 2295.514 us; speedup vs baseline: 2.0229x; 1.3640x over previous
//
#include <hip/hip_runtime.h>
#include <cmath>

#define T_STEPS 128
#define B_ENV   1024
#define OBS_D   63
#define HID     256
#define NA      6

// workspace layout (float-slot offsets)
#define OFF_W1T    0         // 16384   fp32 W1^T (row 63 zero-padded)
#define OFF_W2T    16384     // 65536   fp32 W2^T
#define OFF_WIP16  81920     // 131072  uints: half2 Wip16[kk][t*4+m] = W_ih[j][2kk..2kk+1], j=m*256+t
#define OFF_WHP16  212992    // 131072  uints: same packing of W_hh
#define OFF_BIAS   344064    // 1024    fp32 biasp[t*4+m] = (b_ih+b_hh)[m*256+t]
#define OFF_XGP    345088    // TC*1048576 fp32 xg (packed [row][t][m])
// hbuf (fp16 h_t, TC*262144 halfs) follows xgp

typedef _Float16 h2f __attribute__((ext_vector_type(2)));

static __device__ __forceinline__ float fdot2u(unsigned a, unsigned b, float c) {
    return __builtin_amdgcn_fdot2(__builtin_bit_cast(h2f, a),
                                  __builtin_bit_cast(h2f, b), c, false);
}
static __device__ __forceinline__ unsigned packh2(float a, float b) {
    _Float16 ha = (_Float16)a, hb = (_Float16)b;
    unsigned short ua = __builtin_bit_cast(unsigned short, ha);
    unsigned short ub = __builtin_bit_cast(unsigned short, hb);
    return (unsigned)ua | ((unsigned)ub << 16);
}

// ---------------------------------------------------------------- prep ------
__global__ void prep_kernel(const float* __restrict__ W1, const float* __restrict__ W2,
                            const float* __restrict__ W_ih, const float* __restrict__ b_ih,
                            const float* __restrict__ W_hh, const float* __restrict__ b_hh,
                            const float* __restrict__ h0, const float* __restrict__ c0,
                            float* __restrict__ W1T, float* __restrict__ W2T,
                            unsigned* __restrict__ Wip16, unsigned* __restrict__ Whp16,
                            float* __restrict__ biasp,
                            float* __restrict__ hstate, float* __restrict__ cstate)
{
    const int stride = gridDim.x * blockDim.x;
    const int idx0 = blockIdx.x * blockDim.x + threadIdx.x;
    for (int i = idx0; i < 64 * 256; i += stride) {
        int k = i >> 8, j = i & 255;
        W1T[i] = (k < OBS_D) ? W1[j * OBS_D + k] : 0.f;
    }
    for (int i = idx0; i < 256 * 256; i += stride) {
        int k = i >> 8, j = i & 255;
        W2T[i] = W2[j * 256 + k];
    }
    for (int i = idx0; i < 128 * 1024; i += stride) {
        int kk = i >> 10, r = i & 1023;
        int t = r >> 2, m = r & 3;
        int j = m * 256 + t;
        Wip16[i] = packh2(W_ih[j * 256 + 2 * kk], W_ih[j * 256 + 2 * kk + 1]);
        Whp16[i] = packh2(W_hh[j * 256 + 2 * kk], W_hh[j * 256 + 2 * kk + 1]);
    }
    for (int i = idx0; i < 1024; i += stride) {
        int t = i >> 2, m = i & 3;
        int j = m * 256 + t;
        biasp[i] = b_ih[j] + b_hh[j];
    }
    for (int i = idx0; i < B_ENV * HID; i += stride) {
        hstate[i] = h0[i];
        cstate[i] = c0[i];
    }
}

// ------------------------------------------------- fused MLP -> xg ----------
// 32 rows/block, 256 threads. LDS: 8K + 32K + 16.9K = 57 KB (2 blocks/CU).
__global__ __launch_bounds__(256) void mlp_xg_kernel(
    const float* __restrict__ x, const float* __restrict__ b1, const float* __restrict__ b2,
    const float* __restrict__ W1T, const float* __restrict__ W2T,
    const unsigned* __restrict__ Wip16, const float* __restrict__ biasp,
    float* __restrict__ xgp, long grow0)
{
    __shared__ float xs[32][64];
    __shared__ float h1s[32][256];
    __shared__ unsigned h2s2[32][132];   // half2 h2, 128 words + pad
    const int t = threadIdx.x;
    const long lrow0 = (long)blockIdx.x * 32;
    const long row0 = grow0 + lrow0;

    for (int i = t; i < 32 * OBS_D; i += 256) {
        int r = i / OBS_D, k = i - r * OBS_D;
        xs[r][k] = x[row0 * OBS_D + i];
    }
    if (t < 32) xs[t][63] = 0.f;
    __syncthreads();

    // phase 1: h1 = tanh(x @ W1^T + b1); thread t owns column t
    float acc[32];
#pragma unroll
    for (int r = 0; r < 32; ++r) acc[r] = 0.f;
    for (int k0 = 0; k0 < 64; k0 += 4) {
        float w0 = W1T[(k0 + 0) * 256 + t];
        float w1 = W1T[(k0 + 1) * 256 + t];
        float w2 = W1T[(k0 + 2) * 256 + t];
        float w3 = W1T[(k0 + 3) * 256 + t];
#pragma unroll
        for (int r = 0; r < 32; ++r) {
            float4 hv = *(const float4*)&xs[r][k0];
            acc[r] += hv.x * w0 + hv.y * w1 + hv.z * w2 + hv.w * w3;
        }
    }
    {
        float b = b1[t];
#pragma unroll
        for (int r = 0; r < 32; ++r) h1s[r][t] = tanhf(acc[r] + b);
    }
    __syncthreads();

    // phase 2: h2 = tanh(h1 @ W2^T + b2), stored to LDS as fp16
#pragma unroll
    for (int r = 0; r < 32; ++r) acc[r] = 0.f;
    for (int k0 = 0; k0 < 256; k0 += 4) {
        float w0 = W2T[(k0 + 0) * 256 + t];
        float w1 = W2T[(k0 + 1) * 256 + t];
        float w2 = W2T[(k0 + 2) * 256 + t];
        float w3 = W2T[(k0 + 3) * 256 + t];
#pragma unroll
        for (int r = 0; r < 32; ++r) {
            float4 hv = *(const float4*)&h1s[r][k0];
            acc[r] += hv.x * w0 + hv.y * w1 + hv.z * w2 + hv.w * w3;
        }
    }
    {
        float b = b2[t];
#pragma unroll
        for (int r = 0; r < 32; ++r)
            ((_Float16*)&h2s2[r][0])[t] = (_Float16)tanhf(acc[r] + b);
    }
    __syncthreads();

    // phase 3: xg = h2 @ W_ih^T + bias via v_dot2_f32_f16
    const float4 bias4 = *(const float4*)&biasp[4 * t];
    const uint4* Wip4 = (const uint4*)Wip16;
#pragma unroll 1
    for (int g = 0; g < 2; ++g) {
        float a4[16][4];
#pragma unroll
        for (int r = 0; r < 16; ++r)
#pragma unroll
            for (int m = 0; m < 4; ++m) a4[r][m] = 0.f;
        uint4 w = Wip4[t];
#pragma unroll 4
        for (int kk = 0; kk < 128; ++kk) {
            uint4 cw = w;
            if (kk + 1 < 128) w = Wip4[(kk + 1) * 256 + t];
#pragma unroll
            for (int r = 0; r < 16; ++r) {
                unsigned hv = h2s2[g * 16 + r][kk];
                a4[r][0] = fdot2u(hv, cw.x, a4[r][0]);
                a4[r][1] = fdot2u(hv, cw.y, a4[r][1]);
                a4[r][2] = fdot2u(hv, cw.z, a4[r][2]);
                a4[r][3] = fdot2u(hv, cw.w, a4[r][3]);
            }
        }
#pragma unroll
        for (int r = 0; r < 16; ++r) {
            float4 o;
            o.x = a4[r][0] + bias4.x;
            o.y = a4[r][1] + bias4.y;
            o.z = a4[r][2] + bias4.z;
            o.w = a4[r][3] + bias4.w;
            *(float4*)&xgp[(lrow0 + g * 16 + r) * 1024 + 4 * t] = o;
        }
    }
}

// ------------------------------------------------- LSTM scan ----------------
// 256 blocks x 256 threads; block owns 4 batch rows. fp16 dot2 matvec with
// 8-deep W prefetch (hides L2 latency) and transposed h in LDS (one uniform
// ds_read_b128 broadcast per k-pair). fp32 cell state and gate math.
__global__ __launch_bounds__(256) void lstm_chunk_kernel(
    const float* __restrict__ xgp, const int* __restrict__ done,
    const unsigned* __restrict__ Whp16,
    _Float16* __restrict__ hbuf,
    float* __restrict__ hstate, float* __restrict__ cstate,
    int step0, int nsteps)
{
    __shared__ uint4 hs2t[128];          // hs2t[kk] = half2 of rows 0..3 at units 2kk,2kk+1
    const int t = threadIdx.x;
    const int rb0 = blockIdx.x * 4;

    float c[4], hlast[4];
#pragma unroll
    for (int r = 0; r < 4; ++r) {
        float hv = hstate[(rb0 + r) * 256 + t];
        hlast[r] = hv;
        ((_Float16*)&hs2t[t >> 1])[2 * r + (t & 1)] = (_Float16)hv;
        c[r] = cstate[(rb0 + r) * 256 + t];
    }
    __syncthreads();

    const uint4* W4 = (const uint4*)Whp16;
    const float4* xgp4 = (const float4*)xgp;

    // 8-deep W prefetch ring; wrap-around keeps it self-renewing across steps
    uint4 wbuf[8];
#pragma unroll
    for (int q = 0; q < 8; ++q) wbuf[q] = W4[q * 256 + t];

    for (int s = 0; s < nsteps; ++s) {
        const long growbase = (long)(step0 + s) * B_ENV + rb0;  // done index
        const long lrowbase = (long)s * B_ENV + rb0;            // xg/hbuf index

        float msk[4];
#pragma unroll
        for (int r = 0; r < 4; ++r) msk[r] = 1.f - (float)done[growbase + r];

        float4 xv[4];
#pragma unroll
        for (int r = 0; r < 4; ++r) xv[r] = xgp4[(lrowbase + r) * 256 + t];

        float acc[4][4];
#pragma unroll
        for (int r = 0; r < 4; ++r)
#pragma unroll
            for (int m = 0; m < 4; ++m) acc[r][m] = 0.f;

#pragma unroll 2
        for (int g = 0; g < 128; g += 8) {
#pragma unroll
            for (int q = 0; q < 8; ++q) {
                const int kk = g + q;
                uint4 cw = wbuf[q];
                wbuf[q] = W4[(((kk + 8) & 127) * 256) + t];
                uint4 hv = hs2t[kk];
                acc[0][0] = fdot2u(hv.x, cw.x, acc[0][0]);
                acc[0][1] = fdot2u(hv.x, cw.y, acc[0][1]);
                acc[0][2] = fdot2u(hv.x, cw.z, acc[0][2]);
                acc[0][3] = fdot2u(hv.x, cw.w, acc[0][3]);
                acc[1][0] = fdot2u(hv.y, cw.x, acc[1][0]);
                acc[1][1] = fdot2u(hv.y, cw.y, acc[1][1]);
                acc[1][2] = fdot2u(hv.y, cw.z, acc[1][2]);
                acc[1][3] = fdot2u(hv.y, cw.w, acc[1][3]);
                acc[2][0] = fdot2u(hv.z, cw.x, acc[2][0]);
                acc[2][1] = fdot2u(hv.z, cw.y, acc[2][1]);
                acc[2][2] = fdot2u(hv.z, cw.z, acc[2][2]);
                acc[2][3] = fdot2u(hv.z, cw.w, acc[2][3]);
                acc[3][0] = fdot2u(hv.w, cw.x, acc[3][0]);
                acc[3][1] = fdot2u(hv.w, cw.y, acc[3][1]);
                acc[3][2] = fdot2u(hv.w, cw.z, acc[3][2]);
                acc[3][3] = fdot2u(hv.w, cw.w, acc[3][3]);
            }
        }
        __syncthreads();   // matvec reads of hs2t complete

#pragma unroll
        for (int r = 0; r < 4; ++r) {
            float gi = xv[r].x + msk[r] * acc[r][0];
            float gf = xv[r].y + msk[r] * acc[r][1];
            float gg = xv[r].z + msk[r] * acc[r][2];
            float go = xv[r].w + msk[r] * acc[r][3];
            float si = 1.f / (1.f + expf(-gi));
            float sf = 1.f / (1.f + expf(-gf));
            float so = 1.f / (1.f + expf(-go));
            float cn = sf * (c[r] * msk[r]) + si * tanhf(gg);
            c[r] = cn;
            float hn = so * tanhf(cn);
            hlast[r] = hn;
            ((_Float16*)&hs2t[t >> 1])[2 * r + (t & 1)] = (_Float16)hn;
            hbuf[(lrowbase + r) * 256 + t] = (_Float16)hn;
        }
        __syncthreads();   // hs2t updated for next step
    }

#pragma unroll
    for (int r = 0; r < 4; ++r) {
        hstate[(rb0 + r) * 256 + t] = hlast[r];
        cstate[(rb0 + r) * 256 + t] = c[r];
    }
}

// ------------------------------------------------- heads --------------------
// 64 rows/block; actor+critic = 7 dots of 256 per row, fp16 dot2 from LDS.
__global__ __launch_bounds__(256) void heads_kernel(
    const _Float16* __restrict__ hbuf,
    const float* __restrict__ Wa, const float* __restrict__ ba,
    const float* __restrict__ Wc, const float* __restrict__ bc,
    float* __restrict__ out, int step0)
{
    __shared__ unsigned hsu[64][132];    // 64 rows of half2 h
    __shared__ unsigned hwu[7][132];     // 7 head rows as half2
    __shared__ float hbias[8];
    const int t = threadIdx.x;
    const long lrow0 = (long)blockIdx.x * 64;

    for (int i = t; i < 7 * 128; i += 256) {
        int a = i >> 7, kk = i & 127;
        float f0 = (a < 6) ? Wa[a * 256 + 2 * kk] : Wc[2 * kk];
        float f1 = (a < 6) ? Wa[a * 256 + 2 * kk + 1] : Wc[2 * kk + 1];
        hwu[a][kk] = packh2(f0, f1);
    }
    if (t < 7) hbias[t] = (t < 6) ? ba[t] : bc[0];

    const uint4* src = (const uint4*)(hbuf + lrow0 * 256);
    for (int i = t; i < 2048; i += 256) {
        int row = i >> 5, c8 = i & 31;
        *(uint4*)&hsu[row][c8 * 4] = src[i];
    }
    __syncthreads();

#pragma unroll 2
    for (int p = 0; p < 2; ++p) {
        int task = p * 256 + t;
        if (task < 448) {
            int row = task / 7, a = task - row * 7;
            float s = 0.f;
#pragma unroll 8
            for (int kk = 0; kk < 128; ++kk)
                s = fdot2u(hsu[row][kk], hwu[a][kk], s);
            out[((long)step0 * B_ENV + lrow0 + row) * 7 + a] = s + hbias[a];
        }
    }
}

// ---------------------------------------------------------------- launch ----
extern "C" void kernel_launch(void* const* d_in, const int* in_sizes, int n_in,
                              void* d_out, int out_size, void* d_ws, size_t ws_size,
                              hipStream_t stream) {
    const float* x    = (const float*)d_in[0];
    const int*   done = (const int*)  d_in[1];
    const float* h0   = (const float*)d_in[2];
    const float* c0   = (const float*)d_in[3];
    const float* W1   = (const float*)d_in[4];
    const float* b1   = (const float*)d_in[5];
    const float* W2   = (const float*)d_in[6];
    const float* b2   = (const float*)d_in[7];
    const float* W_ih = (const float*)d_in[8];
    const float* b_ih = (const float*)d_in[9];
    const float* W_hh = (const float*)d_in[10];
    const float* b_hh = (const float*)d_in[11];
    const float* Wa   = (const float*)d_in[12];
    const float* ba   = (const float*)d_in[13];
    const float* Wc   = (const float*)d_in[14];
    const float* bc   = (const float*)d_in[15];

    float* ws       = (float*)d_ws;
    float* W1T      = ws + OFF_W1T;
    float* W2T      = ws + OFF_W2T;
    unsigned* Wip16 = (unsigned*)(ws + OFF_WIP16);
    unsigned* Whp16 = (unsigned*)(ws + OFF_WHP16);
    float* biasp    = ws + OFF_BIAS;
    float* xgp      = ws + OFF_XGP;

    float* out = (float*)d_out;
    float* hT  = out + (size_t)T_STEPS * B_ENV * (NA + 1);
    float* cT  = hT + (size_t)B_ENV * HID;

    // largest power-of-two chunk: xgp (TC*1M fp32) + hbuf (TC*128K slots)
    const size_t ws_floats = ws_size / sizeof(float);
    int TC = T_STEPS;
    while (TC > 1 && (size_t)OFF_XGP + (size_t)TC * (1048576 + 131072) > ws_floats) TC >>= 1;
    _Float16* hbuf = (_Float16*)(ws + OFF_XGP + (size_t)TC * 1048576);

    prep_kernel<<<512, 256, 0, stream>>>(W1, W2, W_ih, b_ih, W_hh, b_hh, h0, c0,
                                         W1T, W2T, Wip16, Whp16, biasp, hT, cT);
    for (int step0 = 0; step0 < T_STEPS; step0 += TC) {
        mlp_xg_kernel<<<TC * 32, 256, 0, stream>>>(
            x, b1, b2, W1T, W2T, Wip16, biasp, xgp, (long)step0 * B_ENV);
        lstm_chunk_kernel<<<B_ENV / 4, 256, 0, stream>>>(
            xgp, done, Whp16, hbuf, hT, cT, step0, TC);
        heads_kernel<<<TC * 16, 256, 0, stream>>>(
            hbuf, Wa, ba, Wc, bc, out, step0);
    }
}

// Round 11
// 1567.775 us; speedup vs baseline: 2.9619x; 1.4642x over previous
//
#include <hip/hip_runtime.h>
#include <cmath>

#define T_STEPS 128
#define B_ENV   1024
#define OBS_D   63
#define HID     256
#define NA      6

// workspace layout (float-slot offsets)
#define OFF_W1T    0         // 16384   fp32 W1^T (row 63 zero-padded)
#define OFF_W2M    16384     // 32768   uints: MFMA-packed fp16 W2 (16nt x 8kt x 64lane x 4w)
#define OFF_WHP16  49152     // 131072  uints: half2 Whp16[kk][t*4+m] (lstm)
#define OFF_WIPM   180224    // 131072  uints: MFMA-packed fp16 W_ih (64nt x 8kt x 64lane x 4w)
#define OFF_BIAS   311296    // 1024    fp32 biasp[t*4+m] = (b_ih+b_hh)[m*256+t]
#define OFF_XGP    312320    // TC*1048576 fp32 xg (packed [row][t][m]); hbuf follows

typedef _Float16 h2f  __attribute__((ext_vector_type(2)));
typedef _Float16 f16x8 __attribute__((ext_vector_type(8)));
typedef float    f32x4 __attribute__((ext_vector_type(4)));

static __device__ __forceinline__ float fdot2u(unsigned a, unsigned b, float c) {
    return __builtin_amdgcn_fdot2(__builtin_bit_cast(h2f, a),
                                  __builtin_bit_cast(h2f, b), c, false);
}
static __device__ __forceinline__ unsigned packh2(float a, float b) {
    _Float16 ha = (_Float16)a, hb = (_Float16)b;
    unsigned short ua = __builtin_bit_cast(unsigned short, ha);
    unsigned short ub = __builtin_bit_cast(unsigned short, hb);
    return (unsigned)ua | ((unsigned)ub << 16);
}

// ---------------------------------------------------------------- prep ------
__global__ void prep_kernel(const float* __restrict__ W1, const float* __restrict__ W2,
                            const float* __restrict__ W_ih, const float* __restrict__ b_ih,
                            const float* __restrict__ W_hh, const float* __restrict__ b_hh,
                            const float* __restrict__ h0, const float* __restrict__ c0,
                            float* __restrict__ W1T, unsigned* __restrict__ W2M,
                            unsigned* __restrict__ WipM, unsigned* __restrict__ Whp16,
                            float* __restrict__ biasp,
                            float* __restrict__ hstate, float* __restrict__ cstate)
{
    const int stride = gridDim.x * blockDim.x;
    const int idx0 = blockIdx.x * blockDim.x + threadIdx.x;
    for (int i = idx0; i < 64 * 256; i += stride) {
        int k = i >> 8, j = i & 255;
        W1T[i] = (k < OBS_D) ? W1[j * OBS_D + k] : 0.f;
    }
    // W2M: MFMA B-frag packing. B[k][c] = W2[c][k]; frag word w of lane l,
    // tile (nt,kt): c = nt*16+(l&15), k = kt*32+((l>>4)&3)*8+2w
    for (int i = idx0; i < 32768; i += stride) {
        int w = i & 3, l = (i >> 2) & 63, kt = (i >> 8) & 7, nt = i >> 11;
        int c = nt * 16 + (l & 15);
        int k = kt * 32 + ((l >> 4) & 3) * 8 + 2 * w;
        W2M[i] = packh2(W2[c * 256 + k], W2[c * 256 + k + 1]);
    }
    // WipM: same packing; packed output col c = 4t+m -> W_ih row j = (c&3)*256+(c>>2)
    for (int i = idx0; i < 131072; i += stride) {
        int w = i & 3, l = (i >> 2) & 63, kt = (i >> 8) & 7, nt = i >> 11;
        int c = nt * 16 + (l & 15);
        int j = (c & 3) * 256 + (c >> 2);
        int k = kt * 32 + ((l >> 4) & 3) * 8 + 2 * w;
        WipM[i] = packh2(W_ih[j * 256 + k], W_ih[j * 256 + k + 1]);
    }
    // Whp16 (lstm): half2 Whp16[kk][t*4+m] = W_hh[m*256+t][2kk..2kk+1]
    for (int i = idx0; i < 131072; i += stride) {
        int kk = i >> 10, r = i & 1023;
        int tt = r >> 2, m = r & 3;
        int j = m * 256 + tt;
        Whp16[i] = packh2(W_hh[j * 256 + 2 * kk], W_hh[j * 256 + 2 * kk + 1]);
    }
    for (int i = idx0; i < 1024; i += stride) {
        int tt = i >> 2, m = i & 3;
        int j = m * 256 + tt;
        biasp[i] = b_ih[j] + b_hh[j];
    }
    for (int i = idx0; i < B_ENV * HID; i += stride) {
        hstate[i] = h0[i];
        cstate[i] = c0[i];
    }
}

// ------------------------------------------------- fused MLP -> xg ----------
// 32 rows/block, 256 threads (4 waves). Phase1 fp32 VALU; phases 2+3 MFMA
// 16x16x32_f16. LDS ~42 KB. A-frags from padded [32][132] half LDS (2-way
// bank alias = free); B-frags pre-packed per-lane in prep, 8-deep ring.
__global__ __launch_bounds__(256) void mlp_xg_kernel(
    const float* __restrict__ x, const float* __restrict__ b1, const float* __restrict__ b2,
    const float* __restrict__ W1T, const unsigned* __restrict__ W2M,
    const unsigned* __restrict__ WipM, const float* __restrict__ biasp,
    float* __restrict__ xgp, long grow0)
{
    __shared__ float xs[32][64];
    __shared__ unsigned h1h[32][132];    // fp16 h1, padded
    __shared__ unsigned h2h[32][132];    // fp16 h2, padded
    const int t = threadIdx.x;
    const int wid = t >> 6, lane = t & 63;
    const int r16 = lane & 15, kg = lane >> 4;
    const long lrow0 = (long)blockIdx.x * 32;
    const long row0 = grow0 + lrow0;

    for (int i = t; i < 32 * OBS_D; i += 256) {
        int r = i / OBS_D, k = i - r * OBS_D;
        xs[r][k] = x[row0 * OBS_D + i];
    }
    if (t < 32) xs[t][63] = 0.f;
    __syncthreads();

    // phase 1 (fp32): h1 = tanh(x @ W1^T + b1); thread t owns column t
    {
        float acc[32];
#pragma unroll
        for (int r = 0; r < 32; ++r) acc[r] = 0.f;
        for (int k0 = 0; k0 < 64; k0 += 4) {
            float w0 = W1T[(k0 + 0) * 256 + t];
            float w1 = W1T[(k0 + 1) * 256 + t];
            float w2 = W1T[(k0 + 2) * 256 + t];
            float w3 = W1T[(k0 + 3) * 256 + t];
#pragma unroll
            for (int r = 0; r < 32; ++r) {
                float4 hv = *(const float4*)&xs[r][k0];
                acc[r] += hv.x * w0 + hv.y * w1 + hv.z * w2 + hv.w * w3;
            }
        }
        float b = b1[t];
#pragma unroll
        for (int r = 0; r < 32; ++r)
            ((_Float16*)&h1h[r][0])[t] = (_Float16)tanhf(acc[r] + b);
    }
    __syncthreads();

    // phase 2 (MFMA): h2 = tanh(h1 @ W2^T + b2) -> h2h fp16
    {
        f32x4 acc2[2][4];
#pragma unroll
        for (int m = 0; m < 2; ++m)
#pragma unroll
            for (int n = 0; n < 4; ++n)
#pragma unroll
                for (int e = 0; e < 4; ++e) acc2[m][n][e] = 0.f;
        const uint4* B4 = (const uint4*)W2M;
        uint4 ring[8];
#pragma unroll
        for (int q = 0; q < 8; ++q) {
            int nt = wid * 4 + (q & 3), kt = q >> 2;
            ring[q] = B4[(nt * 8 + kt) * 64 + lane];
        }
#pragma unroll
        for (int kt = 0; kt < 8; ++kt) {
            f16x8 a0 = __builtin_bit_cast(f16x8, *(const uint4*)&h1h[r16][kt * 16 + kg * 4]);
            f16x8 a1 = __builtin_bit_cast(f16x8, *(const uint4*)&h1h[16 + r16][kt * 16 + kg * 4]);
#pragma unroll
            for (int n = 0; n < 4; ++n) {
                int fi = kt * 4 + n;
                uint4 cb = ring[fi & 7];
                int fj = fi + 8;
                if (fj < 32) {
                    int nt2 = wid * 4 + (fj & 3), kt2 = fj >> 2;
                    ring[fi & 7] = B4[(nt2 * 8 + kt2) * 64 + lane];
                }
                f16x8 bf = __builtin_bit_cast(f16x8, cb);
                acc2[0][n] = __builtin_amdgcn_mfma_f32_16x16x32_f16(a0, bf, acc2[0][n], 0, 0, 0);
                acc2[1][n] = __builtin_amdgcn_mfma_f32_16x16x32_f16(a1, bf, acc2[1][n], 0, 0, 0);
            }
        }
#pragma unroll
        for (int n = 0; n < 4; ++n) {
            int col = (wid * 4 + n) * 16 + r16;
            float bb = b2[col];
#pragma unroll
            for (int m = 0; m < 2; ++m)
#pragma unroll
                for (int reg = 0; reg < 4; ++reg) {
                    int row = m * 16 + kg * 4 + reg;
                    ((_Float16*)&h2h[row][0])[col] = (_Float16)tanhf(acc2[m][n][reg] + bb);
                }
        }
    }
    __syncthreads();

    // phase 3 (MFMA): xg = h2 @ W_ih^T + bias -> xgp fp32 [row][c], c=4t+m
    {
        f32x4 acc3[2][16];
#pragma unroll
        for (int m = 0; m < 2; ++m)
#pragma unroll
            for (int n = 0; n < 16; ++n)
#pragma unroll
                for (int e = 0; e < 4; ++e) acc3[m][n][e] = 0.f;
        const uint4* B4 = (const uint4*)WipM;
        const int nbase = wid * 16;
        uint4 ring[8];
#pragma unroll
        for (int q = 0; q < 8; ++q)
            ring[q] = B4[((nbase + q) * 8 + 0) * 64 + lane];
        for (int kt = 0; kt < 8; ++kt) {
            f16x8 a0 = __builtin_bit_cast(f16x8, *(const uint4*)&h2h[r16][kt * 16 + kg * 4]);
            f16x8 a1 = __builtin_bit_cast(f16x8, *(const uint4*)&h2h[16 + r16][kt * 16 + kg * 4]);
#pragma unroll
            for (int n = 0; n < 16; ++n) {
                int fi = kt * 16 + n;
                uint4 cb = ring[fi & 7];
                int fj = fi + 8;
                if (fj < 128)
                    ring[fi & 7] = B4[((nbase + (fj & 15)) * 8 + (fj >> 4)) * 64 + lane];
                f16x8 bf = __builtin_bit_cast(f16x8, cb);
                acc3[0][n] = __builtin_amdgcn_mfma_f32_16x16x32_f16(a0, bf, acc3[0][n], 0, 0, 0);
                acc3[1][n] = __builtin_amdgcn_mfma_f32_16x16x32_f16(a1, bf, acc3[1][n], 0, 0, 0);
            }
        }
#pragma unroll
        for (int n = 0; n < 16; ++n) {
            int c = (nbase + n) * 16 + r16;
            float bb = biasp[c];
#pragma unroll
            for (int m = 0; m < 2; ++m)
#pragma unroll
                for (int reg = 0; reg < 4; ++reg) {
                    int row = m * 16 + kg * 4 + reg;
                    xgp[(lrow0 + row) * 1024 + c] = acc3[m][n][reg] + bb;
                }
        }
    }
}

// ------------------------------------------------- LSTM scan ----------------
// 256 blocks x 256 threads; block owns 4 batch rows. fp16 dot2 matvec with
// 8-deep W prefetch ring and transposed h in LDS (uniform b128 broadcast).
__global__ __launch_bounds__(256) void lstm_chunk_kernel(
    const float* __restrict__ xgp, const int* __restrict__ done,
    const unsigned* __restrict__ Whp16,
    _Float16* __restrict__ hbuf,
    float* __restrict__ hstate, float* __restrict__ cstate,
    int step0, int nsteps)
{
    __shared__ uint4 hs2t[128];          // hs2t[kk] = half2 of rows 0..3 at units 2kk,2kk+1
    const int t = threadIdx.x;
    const int rb0 = blockIdx.x * 4;

    float c[4], hlast[4];
#pragma unroll
    for (int r = 0; r < 4; ++r) {
        float hv = hstate[(rb0 + r) * 256 + t];
        hlast[r] = hv;
        ((_Float16*)&hs2t[t >> 1])[2 * r + (t & 1)] = (_Float16)hv;
        c[r] = cstate[(rb0 + r) * 256 + t];
    }
    __syncthreads();

    const uint4* W4 = (const uint4*)Whp16;
    const float4* xgp4 = (const float4*)xgp;

    uint4 wbuf[8];
#pragma unroll
    for (int q = 0; q < 8; ++q) wbuf[q] = W4[q * 256 + t];

    for (int s = 0; s < nsteps; ++s) {
        const long growbase = (long)(step0 + s) * B_ENV + rb0;
        const long lrowbase = (long)s * B_ENV + rb0;

        float msk[4];
#pragma unroll
        for (int r = 0; r < 4; ++r) msk[r] = 1.f - (float)done[growbase + r];

        float4 xv[4];
#pragma unroll
        for (int r = 0; r < 4; ++r) xv[r] = xgp4[(lrowbase + r) * 256 + t];

        float acc[4][4];
#pragma unroll
        for (int r = 0; r < 4; ++r)
#pragma unroll
            for (int m = 0; m < 4; ++m) acc[r][m] = 0.f;

#pragma unroll 2
        for (int g = 0; g < 128; g += 8) {
#pragma unroll
            for (int q = 0; q < 8; ++q) {
                const int kk = g + q;
                uint4 cw = wbuf[q];
                wbuf[q] = W4[(((kk + 8) & 127) * 256) + t];
                uint4 hv = hs2t[kk];
                acc[0][0] = fdot2u(hv.x, cw.x, acc[0][0]);
                acc[0][1] = fdot2u(hv.x, cw.y, acc[0][1]);
                acc[0][2] = fdot2u(hv.x, cw.z, acc[0][2]);
                acc[0][3] = fdot2u(hv.x, cw.w, acc[0][3]);
                acc[1][0] = fdot2u(hv.y, cw.x, acc[1][0]);
                acc[1][1] = fdot2u(hv.y, cw.y, acc[1][1]);
                acc[1][2] = fdot2u(hv.y, cw.z, acc[1][2]);
                acc[1][3] = fdot2u(hv.y, cw.w, acc[1][3]);
                acc[2][0] = fdot2u(hv.z, cw.x, acc[2][0]);
                acc[2][1] = fdot2u(hv.z, cw.y, acc[2][1]);
                acc[2][2] = fdot2u(hv.z, cw.z, acc[2][2]);
                acc[2][3] = fdot2u(hv.z, cw.w, acc[2][3]);
                acc[3][0] = fdot2u(hv.w, cw.x, acc[3][0]);
                acc[3][1] = fdot2u(hv.w, cw.y, acc[3][1]);
                acc[3][2] = fdot2u(hv.w, cw.z, acc[3][2]);
                acc[3][3] = fdot2u(hv.w, cw.w, acc[3][3]);
            }
        }
        __syncthreads();

#pragma unroll
        for (int r = 0; r < 4; ++r) {
            float gi = xv[r].x + msk[r] * acc[r][0];
            float gf = xv[r].y + msk[r] * acc[r][1];
            float gg = xv[r].z + msk[r] * acc[r][2];
            float go = xv[r].w + msk[r] * acc[r][3];
            float si = 1.f / (1.f + expf(-gi));
            float sf = 1.f / (1.f + expf(-gf));
            float so = 1.f / (1.f + expf(-go));
            float cn = sf * (c[r] * msk[r]) + si * tanhf(gg);
            c[r] = cn;
            float hn = so * tanhf(cn);
            hlast[r] = hn;
            ((_Float16*)&hs2t[t >> 1])[2 * r + (t & 1)] = (_Float16)hn;
            hbuf[(lrowbase + r) * 256 + t] = (_Float16)hn;
        }
        __syncthreads();
    }

#pragma unroll
    for (int r = 0; r < 4; ++r) {
        hstate[(rb0 + r) * 256 + t] = hlast[r];
        cstate[(rb0 + r) * 256 + t] = c[r];
    }
}

// ------------------------------------------------- heads --------------------
__global__ __launch_bounds__(256) void heads_kernel(
    const _Float16* __restrict__ hbuf,
    const float* __restrict__ Wa, const float* __restrict__ ba,
    const float* __restrict__ Wc, const float* __restrict__ bc,
    float* __restrict__ out, int step0)
{
    __shared__ unsigned hsu[64][132];
    __shared__ unsigned hwu[7][132];
    __shared__ float hbias[8];
    const int t = threadIdx.x;
    const long lrow0 = (long)blockIdx.x * 64;

    for (int i = t; i < 7 * 128; i += 256) {
        int a = i >> 7, kk = i & 127;
        float f0 = (a < 6) ? Wa[a * 256 + 2 * kk] : Wc[2 * kk];
        float f1 = (a < 6) ? Wa[a * 256 + 2 * kk + 1] : Wc[2 * kk + 1];
        hwu[a][kk] = packh2(f0, f1);
    }
    if (t < 7) hbias[t] = (t < 6) ? ba[t] : bc[0];

    const uint4* src = (const uint4*)(hbuf + lrow0 * 256);
    for (int i = t; i < 2048; i += 256) {
        int row = i >> 5, c8 = i & 31;
        *(uint4*)&hsu[row][c8 * 4] = src[i];
    }
    __syncthreads();

#pragma unroll 2
    for (int p = 0; p < 2; ++p) {
        int task = p * 256 + t;
        if (task < 448) {
            int row = task / 7, a = task - row * 7;
            float s = 0.f;
#pragma unroll 8
            for (int kk = 0; kk < 128; ++kk)
                s = fdot2u(hsu[row][kk], hwu[a][kk], s);
            out[((long)step0 * B_ENV + lrow0 + row) * 7 + a] = s + hbias[a];
        }
    }
}

// ---------------------------------------------------------------- launch ----
extern "C" void kernel_launch(void* const* d_in, const int* in_sizes, int n_in,
                              void* d_out, int out_size, void* d_ws, size_t ws_size,
                              hipStream_t stream) {
    const float* x    = (const float*)d_in[0];
    const int*   done = (const int*)  d_in[1];
    const float* h0   = (const float*)d_in[2];
    const float* c0   = (const float*)d_in[3];
    const float* W1   = (const float*)d_in[4];
    const float* b1   = (const float*)d_in[5];
    const float* W2   = (const float*)d_in[6];
    const float* b2   = (const float*)d_in[7];
    const float* W_ih = (const float*)d_in[8];
    const float* b_ih = (const float*)d_in[9];
    const float* W_hh = (const float*)d_in[10];
    const float* b_hh = (const float*)d_in[11];
    const float* Wa   = (const float*)d_in[12];
    const float* ba   = (const float*)d_in[13];
    const float* Wc   = (const float*)d_in[14];
    const float* bc   = (const float*)d_in[15];

    float* ws       = (float*)d_ws;
    float* W1T      = ws + OFF_W1T;
    unsigned* W2M   = (unsigned*)(ws + OFF_W2M);
    unsigned* Whp16 = (unsigned*)(ws + OFF_WHP16);
    unsigned* WipM  = (unsigned*)(ws + OFF_WIPM);
    float* biasp    = ws + OFF_BIAS;
    float* xgp      = ws + OFF_XGP;

    float* out = (float*)d_out;
    float* hT  = out + (size_t)T_STEPS * B_ENV * (NA + 1);
    float* cT  = hT + (size_t)B_ENV * HID;

    const size_t ws_floats = ws_size / sizeof(float);
    int TC = T_STEPS;
    while (TC > 1 && (size_t)OFF_XGP + (size_t)TC * (1048576 + 131072) > ws_floats) TC >>= 1;
    _Float16* hbuf = (_Float16*)(ws + OFF_XGP + (size_t)TC * 1048576);

    prep_kernel<<<512, 256, 0, stream>>>(W1, W2, W_ih, b_ih, W_hh, b_hh, h0, c0,
                                         W1T, W2M, WipM, Whp16, biasp, hT, cT);
    for (int step0 = 0; step0 < T_STEPS; step0 += TC) {
        mlp_xg_kernel<<<TC * 32, 256, 0, stream>>>(
            x, b1, b2, W1T, W2M, WipM, biasp, xgp, (long)step0 * B_ENV);
        lstm_chunk_kernel<<<B_ENV / 4, 256, 0, stream>>>(
            xgp, done, Whp16, hbuf, hT, cT, step0, TC);
        heads_kernel<<<TC * 16, 256, 0, stream>>>(
            hbuf, Wa, ba, Wc, bc, out, step0);
    }
}